// Round 19
// baseline (181.989 us; speedup 1.0000x reference)
//
#include <hip/hip_runtime.h>
#include <hip/hip_bf16.h>
#include <math.h>

#define NN 200000
#define EE 100000
#define RAWD 172
#define MEMD 100
#define NKT 19            // 15 gi k-tiles (K=480) + 4 gh k-tiles (reuse Xs[0,128))
#define NCT 21            // col-tiles: ct = p*7 + jm (gate-aligned), m = jm*16+i
#define BM 64             // winner nodes per block
#define BML 64            // loser nodes per block
#define NTHR 512          // 8 waves
#define RS 488            // winner X row stride (shorts)
#define RSL 136           // loser X row stride (shorts)
#define NB2 782           // ceil(NN/256)
#define NPACKB 100        // pack blocks appended to scatter grid
#define NBLKF 3200        // fused grid (wblk + lblk <= 3127)

typedef __attribute__((ext_vector_type(8))) short bf16x8;
typedef __attribute__((ext_vector_type(4))) float f32x4;

__device__ inline unsigned short f2bf(float v) {
    __hip_bfloat16 h = __float2bfloat16(v);
    unsigned short u; __builtin_memcpy(&u, &h, 2); return u;
}

__device__ inline ushort4 pack4(float4 v) {
    ushort4 r;
    r.x = f2bf(v.x); r.y = f2bf(v.y); r.z = f2bf(v.z); r.w = f2bf(v.w);
    return r;
}

__device__ inline float bf2f(unsigned short u) {
    unsigned int x = ((unsigned int)u) << 16;
    float f; __builtin_memcpy(&f, &x, 4); return f;
}

__device__ inline float fsigmoid(float x) { return 1.f / (1.f + __expf(-x)); }
__device__ inline float ftanh(float x) { return 1.f - 2.f / (__expf(2.f * x) + 1.f); }

// Branchless cos, f32-only: 2-term Cody-Waite range reduction (exact for
// |x| < ~2^20: k*eps(c1) ~ 1e-10, final rounding ~1e-7 -- far below the
// 0.4% bf16 quantization already applied to X), f32 polys, quadrant select.
__device__ inline float fast_cos(float x) {
    float kf = rintf(x * 0.63661977236758134f);     // x * 2/pi
    int ki = (int)kf;
    const float c0 = 1.57079637050628662109375f;    // f32(pi/2)
    const float c1 = -4.37113900018624283e-8f;      // pi/2 - c0
    float r = fmaf(-kf, c0, x);
    r = fmaf(-kf, c1, r);
    float s = r * r;
    float c = fmaf(s, fmaf(s, fmaf(s, fmaf(s, 2.4801587e-5f, -1.3888889e-3f),
                                   4.1666668e-2f), -0.5f), 1.0f);
    float sn = r * fmaf(s, fmaf(s, fmaf(s, -1.9841270e-4f, 8.3333338e-3f),
                                -1.6666667e-1f), 1.0f);
    float base = (ki & 1) ? sn : c;
    return ((ki + 1) & 2) ? -base : base;
}

// ---- kernel 1: per-node winner via packed atomicMax key = (t<<32)|(eid+1) ----
__global__ void k_winner(const int* __restrict__ src, const int* __restrict__ dst,
                         const int* __restrict__ t, unsigned long long* __restrict__ keys) {
    int e = blockIdx.x * blockDim.x + threadIdx.x;
    if (e >= 2 * EE) return;
    int re = (e < EE) ? e : e - EE;
    int node = (e < EE) ? src[re] : dst[re];
    unsigned long long key =
        ((unsigned long long)(unsigned)t[re] << 32) | (unsigned)(e + 1);
    atomicMax(&keys[node], key);
}

// ---- kernel 2: fused compaction (atomic chunk reservation) + decode + pack ----
// Blocks [0,NB2): count winners/losers via ballot, reserve list slices with one
// atomicAdd each (chunk-contiguous => locality ~= sorted; outputs are
// order-independent => deterministic). Blocks [NB2, NB2+NPACKB): pack Wb.
__global__ void k_scatter2(const unsigned long long* __restrict__ keys,
                           const int* __restrict__ src, const int* __restrict__ dst,
                           const int* __restrict__ lu,
                           int* __restrict__ othC, int* __restrict__ ewC,
                           float* __restrict__ dtvC, float* __restrict__ out_lu,
                           int* __restrict__ list, int* __restrict__ cnt,
                           const float* __restrict__ w_ih, const float* __restrict__ w_hh,
                           unsigned short* __restrict__ Wb) {
    int bid = blockIdx.x, tid = threadIdx.x;
    if (bid >= NB2) {
        // ---- pack role ----
        int id = (bid - NB2) * 256 + tid;
        if (id >= NKT * NCT * 64) return;
        int lane = id & 63;
        int ct = (id >> 6) % NCT;
        int kt = id / (64 * NCT);
        int jm = ct % 7, p = ct / 7;
        int m = jm * 16 + (lane & 15);
        int kl = lane >> 4;
        unsigned short o[8];
#pragma unroll
        for (int j = 0; j < 8; ++j) {
            float v = 0.f;
            if (m < MEMD) {
                int c = p * MEMD + m;
                if (kt < 15) {
                    int k = kt * 32 + kl * 8 + j;
                    if (k < 472) v = w_ih[(size_t)c * 472 + k];
                } else {
                    int kk = (kt - 15) * 32 + kl * 8 + j;
                    if (kk < MEMD) v = w_hh[(size_t)c * MEMD + kk];
                }
            }
            o[j] = f2bf(v);
        }
        uint4 v4; __builtin_memcpy(&v4, o, 16);
        *reinterpret_cast<uint4*>(Wb + (size_t)id * 8) = v4;
        return;
    }
    // ---- compaction role ----
    int n = bid * 256 + tid;
    bool valid = n < NN;
    unsigned long long k = valid ? keys[n] : 0ull;
    bool fW = valid && (k != 0ull);
    bool fL = valid && (k == 0ull);
    unsigned long long mW = __ballot(fW), mL = __ballot(fL);
    int lane = tid & 63, wave = tid >> 6;
    __shared__ int sW[4], sL[4];
    __shared__ int baseWs, baseLs;
    if (lane == 0) { sW[wave] = __popcll(mW); sL[wave] = __popcll(mL); }
    __syncthreads();
    if (tid == 0) {
        int tw = sW[0] + sW[1] + sW[2] + sW[3];
        int tl = sL[0] + sL[1] + sL[2] + sL[3];
        baseWs = atomicAdd(&cnt[0], tw);
        baseLs = atomicAdd(&cnt[1], tl);
    }
    __syncthreads();
    int baseW = baseWs, baseL = baseLs;
    for (int i = 0; i < wave; ++i) { baseW += sW[i]; baseL += sL[i]; }
    unsigned long long below = (1ull << lane) - 1ull;
    if (fW) {
        int pos = baseW + __popcll(mW & below);
        list[pos] = n;
        int w = (int)(k & 0xffffffffull) - 1;
        int re = (w < EE) ? w : w - EE;
        othC[pos] = (w < EE) ? dst[re] : src[re];
        ewC[pos] = re;
        int tt = (int)(k >> 32);
        dtvC[pos] = (float)tt - (float)lu[n];
        out_lu[n] = (float)tt;
    } else if (valid) {
        int pos = baseL + __popcll(mL & below);
        list[NN - 1 - pos] = n;
        out_lu[n] = (float)lu[n];
    }
}

// ---- kernel 3: merged winner/loser, W/L blocks interleaved in bid space ----
__global__ __launch_bounds__(NTHR, 3) void k_fusedWL(
    const float* __restrict__ memory, const float* __restrict__ raw_msg,
    const float* __restrict__ time_w, const float* __restrict__ time_b,
    const float* __restrict__ b_ih, const float* __restrict__ b_hh,
    const int* __restrict__ othC, const int* __restrict__ ewC,
    const float* __restrict__ dtvC, const unsigned short* __restrict__ Wb,
    const int* __restrict__ list, const int* __restrict__ cnt,
    float* __restrict__ out_mem) {
    __shared__ alignas(16) unsigned short Xs[BM * RS];   // 62464 B
    __shared__ int s_node[BM];
    __shared__ int s_oth[BM];
    __shared__ int s_e[BM];
    __shared__ float s_dt[BM];

    const int tid = threadIdx.x;
    const int nW = cnt[0];
    const int nL = NN - nW;
    const int wblk = (nW + BM - 1) / BM;
    const int lblk = (nL + BML - 1) / BML;
    if ((int)blockIdx.x >= wblk + lblk) return;

    // bijective interleave: odd bids -> losers (while available), evens ->
    // winners; tail takes whichever remains. Keeps one gather-heavy loser
    // block co-resident with a winner block on most CUs (phase diversity).
    int bid = blockIdx.x;
    int lid = bid >> 1;
    bool isL = (bid & 1) && (lid < lblk);
    int wid = 0;
    if (!isL) {
        int placedL = lblk < ((bid + 1) >> 1) ? lblk : ((bid + 1) >> 1);
        wid = bid - placedL;
        if (wid >= wblk) { isL = true; lid = bid - wblk; }
    }

    const int w = tid >> 6;
    const int l = tid & 63;
    const int lrow = l & 15, lk = l >> 4;
    const bf16x8* Wbv = reinterpret_cast<const bf16x8*>(Wb);
    const ushort4 z4 = {0, 0, 0, 0};

    auto loadB = [&](bf16x8 (&bb)[3], int kt) {
#pragma unroll
        for (int p = 0; p < 3; ++p)
            bb[p] = Wbv[(kt * NCT + p * 7 + w) * 64 + l];
    };

    if (!isL) {
        // ================= winner path =================
        const int r15 = wid % 15;
        const int r4 = wid & 3;
        auto ktof = [&](int idx) {
            if (idx < 15) { int k = r15 + idx; return k >= 15 ? k - 15 : k; }
            int k = r4 + (idx - 15); return 15 + (k >= 4 ? k - 4 : k);
        };

        bf16x8 b0[3], b1[3];
        if (w < 7) { loadB(b0, ktof(0)); loadB(b1, ktof(1)); }

        const int nbase = wid * BM;
        if (tid < BM) {
            int idx = nbase + tid; if (idx >= nW) idx = nW - 1;  // dup tail: benign
            s_node[tid] = list[idx];
            s_oth[tid] = othC[idx];
            s_e[tid] = ewC[idx];
            s_dt[tid] = dtvC[idx];
        }
        __syncthreads();

        // build X tile [64][480] bf16
        for (int i = tid; i < BM * 25; i += NTHR) {
            int row = i / 25, c = i - row * 25;
            float4 v = *reinterpret_cast<const float4*>(
                memory + (size_t)s_oth[row] * MEMD + 4 * c);
            *reinterpret_cast<ushort4*>(&Xs[row * RS + 100 + 4 * c]) = pack4(v);
        }
        for (int i = tid; i < BM * 43; i += NTHR) {
            int row = i / 43, c = i - row * 43;
            float4 v = *reinterpret_cast<const float4*>(
                raw_msg + (size_t)s_e[row] * RAWD + 4 * c);
            *reinterpret_cast<ushort4*>(&Xs[row * RS + 200 + 4 * c]) = pack4(v);
        }
        for (int i = tid; i < BM * 25; i += NTHR) {
            int row = i / 25, c = i - row * 25;
            float4 v = *reinterpret_cast<const float4*>(
                memory + (size_t)s_node[row] * MEMD + 4 * c);
            *reinterpret_cast<ushort4*>(&Xs[row * RS + 4 * c]) = pack4(v);
        }
        for (int i = tid; i < BM * 25; i += NTHR) {
            int row = i / 25, c = i - row * 25;
            float dt = s_dt[row];
            float4 wv = *reinterpret_cast<const float4*>(time_w + 4 * c);
            float4 bv = *reinterpret_cast<const float4*>(time_b + 4 * c);
            float4 v;
            v.x = fast_cos(__fadd_rn(__fmul_rn(dt, wv.x), bv.x));
            v.y = fast_cos(__fadd_rn(__fmul_rn(dt, wv.y), bv.y));
            v.z = fast_cos(__fadd_rn(__fmul_rn(dt, wv.z), bv.z));
            v.w = fast_cos(__fadd_rn(__fmul_rn(dt, wv.w), bv.w));
            *reinterpret_cast<ushort4*>(&Xs[row * RS + 372 + 4 * c]) = pack4(v);
        }
        if (tid < BM * 2) {
            int row = tid >> 1, c = tid & 1;
            *reinterpret_cast<ushort4*>(&Xs[row * RS + 472 + 4 * c]) = z4;
        }
        __syncthreads();
        if (w >= 7) return;   // wave 7 idle; no barriers follow

        f32x4 accA[3][4];     // [gate p][rowgroup]
        f32x4 acch[4];        // gh-only n-gate accumulator
#pragma unroll
        for (int p = 0; p < 3; ++p)
#pragma unroll
            for (int rg = 0; rg < 4; ++rg) accA[p][rg] = (f32x4){0.f, 0.f, 0.f, 0.f};
#pragma unroll
        for (int rg = 0; rg < 4; ++rg) acch[rg] = (f32x4){0.f, 0.f, 0.f, 0.f};

        auto step = [&](bf16x8 (&bb)[3], int kt) {
            int ao = (kt < 15) ? kt * 32 : (kt - 15) * 32;   // gh tiles reuse Xs[0,128)
            bf16x8 a[4];
#pragma unroll
            for (int rg = 0; rg < 4; ++rg)
                a[rg] = *reinterpret_cast<const bf16x8*>(
                    &Xs[(16 * rg + lrow) * RS + ao + lk * 8]);
#pragma unroll
            for (int p = 0; p < 3; ++p)
#pragma unroll
                for (int rg = 0; rg < 4; ++rg)
                    accA[p][rg] = __builtin_amdgcn_mfma_f32_16x16x32_bf16(a[rg], bb[p], accA[p][rg], 0, 0, 0);
            if (kt >= 15) {
#pragma unroll
                for (int rg = 0; rg < 4; ++rg)
                    acch[rg] = __builtin_amdgcn_mfma_f32_16x16x32_bf16(a[rg], bb[2], acch[rg], 0, 0, 0);
            }
        };

#pragma unroll
        for (int g = 0; g < 18; g += 2) {
            step(b0, ktof(g));     if (g + 2 < NKT) loadB(b0, ktof(g + 2));
            step(b1, ktof(g + 1)); if (g + 3 < NKT) loadB(b1, ktof(g + 3));
        }
        step(b0, ktof(18));

        // register-local epilogue; memory re-read from Xs (bf16)
        const int m = 16 * w + lrow;
        if (m < MEMD) {
            const float bi_r = b_ih[m],       bh_r = b_hh[m];
            const float bi_z = b_ih[100 + m], bh_z = b_hh[100 + m];
            const float bi_n = b_ih[200 + m], bh_n = b_hh[200 + m];
#pragma unroll
            for (int rg = 0; rg < 4; ++rg) {
#pragma unroll
                for (int reg = 0; reg < 4; ++reg) {
                    int row = 16 * rg + lk * 4 + reg;
                    size_t node = (size_t)s_node[row];
                    float mo = bf2f(Xs[row * RS + m]);
                    float rgv = accA[0][rg][reg] + bi_r + bh_r;
                    float zgv = accA[1][rg][reg] + bi_z + bh_z;
                    float ghn = acch[rg][reg] + bh_n;
                    float gin = (accA[2][rg][reg] - acch[rg][reg]) + bi_n;
                    float rr = fsigmoid(rgv);
                    float zz = fsigmoid(zgv);
                    float nv = ftanh(gin + rr * ghn);
                    out_mem[node * MEMD + m] = (1.f - zz) * nv + zz * mo;
                }
            }
        }
    } else {
        // ================= loser path =================
        const int lbase = lid * BML;
        if (lbase >= nL) return;

        const int r4 = bid & 3;
        auto lkt = [&](int idx) { return (r4 + idx) & 3; };

        bf16x8 bl0[3], bl1[3];
        if (w < 7) { loadB(bl0, 15 + lkt(0)); loadB(bl1, 15 + lkt(1)); }

        if (tid < BML) {
            int idx = lbase + tid; if (idx >= nL) idx = nL - 1;  // dup tail: benign
            s_node[tid] = list[NN - 1 - idx];
        }
        __syncthreads();

        float4 vS[4];
#pragma unroll
        for (int f = 0; f < 4; ++f) {
            int i = tid + f * NTHR; int i2 = (i < BML * 25) ? i : 0;
            int row = i2 / 25, c = i2 - row * 25;
            vS[f] = *reinterpret_cast<const float4*>(
                memory + (size_t)s_node[row] * MEMD + 4 * c);
        }
        asm volatile("" ::: "memory");
#pragma unroll
        for (int f = 0; f < 4; ++f) {
            int i = tid + f * NTHR;
            if (i < BML * 25) {
                int row = i / 25, c = i - row * 25;
                *reinterpret_cast<ushort4*>(&Xs[row * RSL + 4 * c]) = pack4(vS[f]);
            }
        }
        if (tid < BML * 7) {
            int row = tid / 7, c = tid - row * 7;
            *reinterpret_cast<ushort4*>(&Xs[row * RSL + 100 + 4 * c]) = z4;
        }
        __syncthreads();
        if (w >= 7) return;

        f32x4 accA[3][4];
#pragma unroll
        for (int p = 0; p < 3; ++p)
#pragma unroll
            for (int rg = 0; rg < 4; ++rg) accA[p][rg] = (f32x4){0.f, 0.f, 0.f, 0.f};

        auto stepL = [&](bf16x8 (&bb)[3], int ktl) {
            bf16x8 a[4];
#pragma unroll
            for (int rg = 0; rg < 4; ++rg)
                a[rg] = *reinterpret_cast<const bf16x8*>(
                    &Xs[(16 * rg + lrow) * RSL + ktl * 32 + lk * 8]);
#pragma unroll
            for (int p = 0; p < 3; ++p)
#pragma unroll
                for (int rg = 0; rg < 4; ++rg)
                    accA[p][rg] = __builtin_amdgcn_mfma_f32_16x16x32_bf16(a[rg], bb[p], accA[p][rg], 0, 0, 0);
        };

        stepL(bl0, lkt(0)); loadB(bl0, 15 + lkt(2));
        stepL(bl1, lkt(1)); loadB(bl1, 15 + lkt(3));
        stepL(bl0, lkt(2));
        stepL(bl1, lkt(3));

        const int m = 16 * w + lrow;
        if (m < MEMD) {
            const float bi_r = b_ih[m],       bh_r = b_hh[m];
            const float bi_z = b_ih[100 + m], bh_z = b_hh[100 + m];
            const float bi_n = b_ih[200 + m], bh_n = b_hh[200 + m];
#pragma unroll
            for (int rg = 0; rg < 4; ++rg) {
#pragma unroll
                for (int reg = 0; reg < 4; ++reg) {
                    int row = 16 * rg + lk * 4 + reg;
                    size_t node = (size_t)s_node[row];
                    float mo = bf2f(Xs[row * RSL + m]);
                    float rgv = accA[0][rg][reg] + bi_r + bh_r;
                    float zgv = accA[1][rg][reg] + bi_z + bh_z;
                    float ghn = accA[2][rg][reg] + bh_n;
                    float gin = bi_n;
                    float rr = fsigmoid(rgv);
                    float zz = fsigmoid(zgv);
                    float nv = ftanh(gin + rr * ghn);
                    out_mem[node * MEMD + m] = (1.f - zz) * nv + zz * mo;
                }
            }
        }
    }
}

extern "C" void kernel_launch(void* const* d_in, const int* in_sizes, int n_in,
                              void* d_out, int out_size, void* d_ws, size_t ws_size,
                              hipStream_t stream) {
    const float* memory = (const float*)d_in[0];
    const float* raw_msg = (const float*)d_in[1];
    const float* time_w = (const float*)d_in[2];
    const float* time_b = (const float*)d_in[3];
    const float* w_ih = (const float*)d_in[4];
    const float* w_hh = (const float*)d_in[5];
    const float* b_ih = (const float*)d_in[6];
    const float* b_hh = (const float*)d_in[7];
    const int* last_update = (const int*)d_in[8];
    const int* src = (const int*)d_in[9];
    const int* dst = (const int*)d_in[10];
    const int* t = (const int*)d_in[11];

    char* ws = (char*)d_ws;
    unsigned long long* keys = (unsigned long long*)ws;       // 1,600,000 B @ 0
    int* othC = (int*)(ws + 1600000);                         //   800,000 B
    int* ewC = (int*)(ws + 2400000);                          //   800,000 B
    float* dtvC = (float*)(ws + 3200000);                     //   800,000 B
    unsigned short* Wb = (unsigned short*)(ws + 4000000);     //   408,576 B
    int* list = (int*)(ws + 4408576);                         //   800,000 B
    int* cnt = (int*)(ws + 5208576);                          //        16 B

    float* out_mem = (float*)d_out;
    float* out_lu = (float*)d_out + (size_t)NN * MEMD;

    hipMemsetAsync(keys, 0, (size_t)NN * 8, stream);
    hipMemsetAsync(cnt, 0, 16, stream);
    k_winner<<<NB2, 256, 0, stream>>>(src, dst, t, keys);
    k_scatter2<<<NB2 + NPACKB, 256, 0, stream>>>(keys, src, dst, last_update,
                                                 othC, ewC, dtvC, out_lu, list, cnt,
                                                 w_ih, w_hh, Wb);
    k_fusedWL<<<NBLKF, NTHR, 0, stream>>>(memory, raw_msg, time_w, time_b, b_ih, b_hh,
                                          othC, ewC, dtvC, Wb, list, cnt, out_mem);
}

// Round 20
// 150.006 us; speedup vs baseline: 1.2132x; 1.2132x over previous
//
#include <hip/hip_runtime.h>
#include <hip/hip_bf16.h>
#include <math.h>

#define NN 200000
#define EE 100000
#define RAWD 172
#define MEMD 100
#define NKT 19            // 15 gi k-tiles (K=480) + 4 gh k-tiles (reuse Xs[0,128))
#define NCT 21            // col-tiles: ct = p*7 + jm (gate-aligned), m = jm*16+i
#define BM 64             // winner nodes per block
#define BML 64            // loser nodes per block
#define NTHR 512          // 8 waves
#define RS 488            // winner X row stride (shorts)
#define RSL 136           // loser X row stride (shorts)
#define NB2 782           // ceil(NN/256)
#define NBLKF 6250        // ceil(NN/64) + ceil(NN/64)

typedef __attribute__((ext_vector_type(8))) short bf16x8;
typedef __attribute__((ext_vector_type(4))) float f32x4;

__device__ inline unsigned short f2bf(float v) {
    __hip_bfloat16 h = __float2bfloat16(v);
    unsigned short u; __builtin_memcpy(&u, &h, 2); return u;
}

__device__ inline ushort4 pack4(float4 v) {
    ushort4 r;
    r.x = f2bf(v.x); r.y = f2bf(v.y); r.z = f2bf(v.z); r.w = f2bf(v.w);
    return r;
}

__device__ inline float bf2f(unsigned short u) {
    unsigned int x = ((unsigned int)u) << 16;
    float f; __builtin_memcpy(&f, &x, 4); return f;
}

__device__ inline float fsigmoid(float x) { return 1.f / (1.f + __expf(-x)); }
__device__ inline float ftanh(float x) { return 1.f - 2.f / (__expf(2.f * x) + 1.f); }

// Branchless cos, f32-only: 2-term Cody-Waite range reduction (k*eps(c1)
// ~1e-10 for |k|<~3e5; final rounding ~1e-7 -- far below the 0.4% bf16
// quantization applied to X), f32 polys, quadrant select via bit tricks.
__device__ inline float fast_cos(float x) {
    float kf = rintf(x * 0.63661977236758134f);     // x * 2/pi
    int ki = (int)kf;
    const float c0 = 1.57079637050628662109375f;    // f32(pi/2)
    const float c1 = -4.37113900018624283e-8f;      // pi/2 - c0
    float r = fmaf(-kf, c0, x);
    r = fmaf(-kf, c1, r);
    float s = r * r;
    float c = fmaf(s, fmaf(s, fmaf(s, fmaf(s, 2.4801587e-5f, -1.3888889e-3f),
                                   4.1666668e-2f), -0.5f), 1.0f);
    float sn = r * fmaf(s, fmaf(s, fmaf(s, -1.9841270e-4f, 8.3333338e-3f),
                                -1.6666667e-1f), 1.0f);
    float base = (ki & 1) ? sn : c;
    return ((ki + 1) & 2) ? -base : base;
}

// ---- kernel 1: per-node winner via packed atomicMax key = (t<<32)|(eid+1) ----
__global__ void k_winner(const int* __restrict__ src, const int* __restrict__ dst,
                         const int* __restrict__ t, unsigned long long* __restrict__ keys) {
    int e = blockIdx.x * blockDim.x + threadIdx.x;
    if (e >= 2 * EE) return;
    int re = (e < EE) ? e : e - EE;
    int node = (e < EE) ? src[re] : dst[re];
    unsigned long long key =
        ((unsigned long long)(unsigned)t[re] << 32) | (unsigned)(e + 1);
    atomicMax(&keys[node], key);
}

// ---- kernel 2a: per-256-block winner counts ----
__global__ void k_count(const unsigned long long* __restrict__ keys,
                        int* __restrict__ blkW) {
    int n = blockIdx.x * 256 + threadIdx.x;
    bool f = (n < NN) && (keys[n] != 0ull);
    unsigned long long m = __ballot(f);
    __shared__ int s[4];
    int wave = threadIdx.x >> 6;
    if ((threadIdx.x & 63) == 0) s[wave] = __popcll(m);
    __syncthreads();
    if (threadIdx.x == 0) blkW[blockIdx.x] = s[0] + s[1] + s[2] + s[3];
}

// ---- kernel 2b: single-block exclusive scan ----
__global__ void k_scan(const int* __restrict__ blkW, int* __restrict__ offW,
                       int* __restrict__ cnt) {
    __shared__ int s[1024];
    int tid = threadIdx.x;
    int v = (tid < NB2) ? blkW[tid] : 0;
    s[tid] = v;
    __syncthreads();
    for (int off = 1; off < 1024; off <<= 1) {
        int t = (tid >= off) ? s[tid - off] : 0;
        __syncthreads();
        s[tid] += t;
        __syncthreads();
    }
    if (tid < NB2) offW[tid] = s[tid] - v;
    if (tid == 0) { cnt[0] = s[1023]; cnt[1] = NN - s[1023]; }
}

// ---- kernel 2c: ordered scatter + decode + compacted aux ----
__global__ void k_scatter(const unsigned long long* __restrict__ keys,
                          const int* __restrict__ src, const int* __restrict__ dst,
                          const int* __restrict__ lu, const int* __restrict__ offW,
                          int* __restrict__ othC, int* __restrict__ ewC,
                          float* __restrict__ dtvC, float* __restrict__ out_lu,
                          int* __restrict__ list) {
    int bid = blockIdx.x, tid = threadIdx.x;
    int n = bid * 256 + tid;
    bool valid = n < NN;
    unsigned long long k = valid ? keys[n] : 0ull;
    bool fW = valid && (k != 0ull);
    bool fL = valid && (k == 0ull);
    unsigned long long mW = __ballot(fW), mL = __ballot(fL);
    int lane = tid & 63, wave = tid >> 6;
    __shared__ int sW[4], sL[4];
    if (lane == 0) { sW[wave] = __popcll(mW); sL[wave] = __popcll(mL); }
    __syncthreads();
    int baseW = 0, baseL = 0;
    for (int i = 0; i < wave; ++i) { baseW += sW[i]; baseL += sL[i]; }
    unsigned long long below = (1ull << lane) - 1ull;
    if (fW) {
        int pos = offW[bid] + baseW + __popcll(mW & below);
        list[pos] = n;
        int w = (int)(k & 0xffffffffull) - 1;
        int re = (w < EE) ? w : w - EE;
        othC[pos] = (w < EE) ? dst[re] : src[re];
        ewC[pos] = re;
        int tt = (int)(k >> 32);
        dtvC[pos] = (float)tt - (float)lu[n];
        out_lu[n] = (float)tt;
    } else if (valid) {
        int pos = (bid * 256 - offW[bid]) + baseL + __popcll(mL & below);
        list[NN - 1 - pos] = n;
        out_lu[n] = (float)lu[n];
    }
}

// ---- kernel 3: pack W, bf16, gate-aligned cols; tiles 15..18 = w_hh local-k ----
__global__ void k_pack(const float* __restrict__ w_ih, const float* __restrict__ w_hh,
                       unsigned short* __restrict__ Wb) {
    int id = blockIdx.x * blockDim.x + threadIdx.x;
    if (id >= NKT * NCT * 64) return;
    int lane = id & 63;
    int ct = (id >> 6) % NCT;
    int kt = id / (64 * NCT);
    int jm = ct % 7, p = ct / 7;
    int m = jm * 16 + (lane & 15);
    int kl = lane >> 4;
    unsigned short o[8];
#pragma unroll
    for (int j = 0; j < 8; ++j) {
        float v = 0.f;
        if (m < MEMD) {
            int c = p * MEMD + m;
            if (kt < 15) {
                int k = kt * 32 + kl * 8 + j;
                if (k < 472) v = w_ih[(size_t)c * 472 + k];
            } else {
                int kk = (kt - 15) * 32 + kl * 8 + j;
                if (kk < MEMD) v = w_hh[(size_t)c * MEMD + kk];
            }
        }
        o[j] = f2bf(v);
    }
    uint4 v4; __builtin_memcpy(&v4, o, 16);
    *reinterpret_cast<uint4*>(Wb + (size_t)id * 8) = v4;
}

// ---- kernel 4: merged winner/loser, register-local epilogue (R18 structure) ----
__global__ __launch_bounds__(NTHR, 4) void k_fusedWL(
    const float* __restrict__ memory, const float* __restrict__ raw_msg,
    const float* __restrict__ time_w, const float* __restrict__ time_b,
    const float* __restrict__ b_ih, const float* __restrict__ b_hh,
    const int* __restrict__ othC, const int* __restrict__ ewC,
    const float* __restrict__ dtvC, const unsigned short* __restrict__ Wb,
    const int* __restrict__ list, const int* __restrict__ cnt,
    float* __restrict__ out_mem) {
    __shared__ alignas(16) unsigned short Xs[BM * RS];   // 62464 B
    __shared__ int s_node[BM];
    __shared__ int s_oth[BM];
    __shared__ int s_e[BM];
    __shared__ float s_dt[BM];

    const int tid = threadIdx.x;
    const int nW = cnt[0];
    const int wblk = (nW + BM - 1) / BM;
    const int w = tid >> 6;
    const int l = tid & 63;
    const int lrow = l & 15, lk = l >> 4;
    const bf16x8* Wbv = reinterpret_cast<const bf16x8*>(Wb);
    const ushort4 z4 = {0, 0, 0, 0};

    auto loadB = [&](bf16x8 (&bb)[3], int kt) {
#pragma unroll
        for (int p = 0; p < 3; ++p)
            bb[p] = Wbv[(kt * NCT + p * 7 + w) * 64 + l];
    };

    if ((int)blockIdx.x < wblk) {
        // ================= winner path =================
        const int r15 = blockIdx.x % 15;
        const int r4 = blockIdx.x & 3;
        auto ktof = [&](int idx) {
            if (idx < 15) { int k = r15 + idx; return k >= 15 ? k - 15 : k; }
            int k = r4 + (idx - 15); return 15 + (k >= 4 ? k - 4 : k);
        };

        // 2-deep B prefetch, issued BEFORE build
        bf16x8 b0[3], b1[3];
        if (w < 7) { loadB(b0, ktof(0)); loadB(b1, ktof(1)); }

        const int nbase = blockIdx.x * BM;
        if (tid < BM) {
            int idx = nbase + tid; if (idx >= nW) idx = nW - 1;  // dup tail: benign
            s_node[tid] = list[idx];
            s_oth[tid] = othC[idx];
            s_e[tid] = ewC[idx];
            s_dt[tid] = dtvC[idx];
        }
        __syncthreads();

        // build X tile [64][480] bf16 — no masks
        for (int i = tid; i < BM * 25; i += NTHR) {
            int row = i / 25, c = i - row * 25;
            float4 v = *reinterpret_cast<const float4*>(
                memory + (size_t)s_oth[row] * MEMD + 4 * c);
            *reinterpret_cast<ushort4*>(&Xs[row * RS + 100 + 4 * c]) = pack4(v);
        }
        for (int i = tid; i < BM * 43; i += NTHR) {
            int row = i / 43, c = i - row * 43;
            float4 v = *reinterpret_cast<const float4*>(
                raw_msg + (size_t)s_e[row] * RAWD + 4 * c);
            *reinterpret_cast<ushort4*>(&Xs[row * RS + 200 + 4 * c]) = pack4(v);
        }
        for (int i = tid; i < BM * 25; i += NTHR) {
            int row = i / 25, c = i - row * 25;
            float4 v = *reinterpret_cast<const float4*>(
                memory + (size_t)s_node[row] * MEMD + 4 * c);
            *reinterpret_cast<ushort4*>(&Xs[row * RS + 4 * c]) = pack4(v);
        }
        for (int i = tid; i < BM * 25; i += NTHR) {
            int row = i / 25, c = i - row * 25;
            float dt = s_dt[row];
            float4 wv = *reinterpret_cast<const float4*>(time_w + 4 * c);
            float4 bv = *reinterpret_cast<const float4*>(time_b + 4 * c);
            float4 v;
            v.x = fast_cos(__fadd_rn(__fmul_rn(dt, wv.x), bv.x));
            v.y = fast_cos(__fadd_rn(__fmul_rn(dt, wv.y), bv.y));
            v.z = fast_cos(__fadd_rn(__fmul_rn(dt, wv.z), bv.z));
            v.w = fast_cos(__fadd_rn(__fmul_rn(dt, wv.w), bv.w));
            *reinterpret_cast<ushort4*>(&Xs[row * RS + 372 + 4 * c]) = pack4(v);
        }
        for (int i = tid; i < BM * 2; i += NTHR) {
            int row = i / 2, c = i - row * 2;
            *reinterpret_cast<ushort4*>(&Xs[row * RS + 472 + 4 * c]) = z4;
        }
        __syncthreads();
        if (w >= 7) return;   // wave 7 idle; no barriers follow

        f32x4 accA[3][4];     // [gate p][rowgroup]
        f32x4 acch[4];        // gh-only n-gate accumulator
#pragma unroll
        for (int p = 0; p < 3; ++p)
#pragma unroll
            for (int rg = 0; rg < 4; ++rg) accA[p][rg] = (f32x4){0.f, 0.f, 0.f, 0.f};
#pragma unroll
        for (int rg = 0; rg < 4; ++rg) acch[rg] = (f32x4){0.f, 0.f, 0.f, 0.f};

        auto step = [&](bf16x8 (&bb)[3], int kt) {
            int ao = (kt < 15) ? kt * 32 : (kt - 15) * 32;   // gh tiles reuse Xs[0,128)
            bf16x8 a[4];
#pragma unroll
            for (int rg = 0; rg < 4; ++rg)
                a[rg] = *reinterpret_cast<const bf16x8*>(
                    &Xs[(16 * rg + lrow) * RS + ao + lk * 8]);
#pragma unroll
            for (int p = 0; p < 3; ++p)
#pragma unroll
                for (int rg = 0; rg < 4; ++rg)
                    accA[p][rg] = __builtin_amdgcn_mfma_f32_16x16x32_bf16(a[rg], bb[p], accA[p][rg], 0, 0, 0);
            if (kt >= 15) {
#pragma unroll
                for (int rg = 0; rg < 4; ++rg)
                    acch[rg] = __builtin_amdgcn_mfma_f32_16x16x32_bf16(a[rg], bb[2], acch[rg], 0, 0, 0);
            }
        };

#pragma unroll
        for (int g = 0; g < 18; g += 2) {
            step(b0, ktof(g));     if (g + 2 < NKT) loadB(b0, ktof(g + 2));
            step(b1, ktof(g + 1)); if (g + 3 < NKT) loadB(b1, ktof(g + 3));
        }
        step(b0, ktof(18));

        // register-local epilogue; memory re-read from Xs (bf16)
        const int m = 16 * w + lrow;
        if (m < MEMD) {
            const float bi_r = b_ih[m],       bh_r = b_hh[m];
            const float bi_z = b_ih[100 + m], bh_z = b_hh[100 + m];
            const float bi_n = b_ih[200 + m], bh_n = b_hh[200 + m];
#pragma unroll
            for (int rg = 0; rg < 4; ++rg) {
#pragma unroll
                for (int reg = 0; reg < 4; ++reg) {
                    int row = 16 * rg + lk * 4 + reg;
                    size_t node = (size_t)s_node[row];
                    float mo = bf2f(Xs[row * RS + m]);
                    float rgv = accA[0][rg][reg] + bi_r + bh_r;
                    float zgv = accA[1][rg][reg] + bi_z + bh_z;
                    float ghn = acch[rg][reg] + bh_n;
                    float gin = (accA[2][rg][reg] - acch[rg][reg]) + bi_n;
                    float rr = fsigmoid(rgv);
                    float zz = fsigmoid(zgv);
                    float nv = ftanh(gin + rr * ghn);
                    out_mem[node * MEMD + m] = (1.f - zz) * nv + zz * mo;
                }
            }
        }
    } else {
        // ================= loser path =================
        const int nL = NN - nW;
        const int lbase = ((int)blockIdx.x - wblk) * BML;
        if (lbase >= nL) return;

        const int r4 = blockIdx.x & 3;
        auto lkt = [&](int idx) { return (r4 + idx) & 3; };

        bf16x8 bl0[3], bl1[3];
        if (w < 7) { loadB(bl0, 15 + lkt(0)); loadB(bl1, 15 + lkt(1)); }

        if (tid < BML) {
            int idx = lbase + tid; if (idx >= nL) idx = nL - 1;  // dup tail: benign
            s_node[tid] = list[NN - 1 - idx];
        }
        __syncthreads();

        // reg-staged self-mem load, forced phase separation
        float4 vS[4];
#pragma unroll
        for (int f = 0; f < 4; ++f) {
            int i = tid + f * NTHR; int i2 = (i < BML * 25) ? i : 0;
            int row = i2 / 25, c = i2 - row * 25;
            vS[f] = *reinterpret_cast<const float4*>(
                memory + (size_t)s_node[row] * MEMD + 4 * c);
        }
        asm volatile("" ::: "memory");
#pragma unroll
        for (int f = 0; f < 4; ++f) {
            int i = tid + f * NTHR;
            if (i < BML * 25) {
                int row = i / 25, c = i - row * 25;
                *reinterpret_cast<ushort4*>(&Xs[row * RSL + 4 * c]) = pack4(vS[f]);
            }
        }
        if (tid < BML * 7) {
            int row = tid / 7, c = tid - row * 7;
            *reinterpret_cast<ushort4*>(&Xs[row * RSL + 100 + 4 * c]) = z4;
        }
        __syncthreads();
        if (w >= 7) return;

        f32x4 accA[3][4];
#pragma unroll
        for (int p = 0; p < 3; ++p)
#pragma unroll
            for (int rg = 0; rg < 4; ++rg) accA[p][rg] = (f32x4){0.f, 0.f, 0.f, 0.f};

        auto stepL = [&](bf16x8 (&bb)[3], int ktl) {
            bf16x8 a[4];
#pragma unroll
            for (int rg = 0; rg < 4; ++rg)
                a[rg] = *reinterpret_cast<const bf16x8*>(
                    &Xs[(16 * rg + lrow) * RSL + ktl * 32 + lk * 8]);
#pragma unroll
            for (int p = 0; p < 3; ++p)
#pragma unroll
                for (int rg = 0; rg < 4; ++rg)
                    accA[p][rg] = __builtin_amdgcn_mfma_f32_16x16x32_bf16(a[rg], bb[p], accA[p][rg], 0, 0, 0);
        };

        stepL(bl0, lkt(0)); loadB(bl0, 15 + lkt(2));
        stepL(bl1, lkt(1)); loadB(bl1, 15 + lkt(3));
        stepL(bl0, lkt(2));
        stepL(bl1, lkt(3));

        const int m = 16 * w + lrow;
        if (m < MEMD) {
            const float bi_r = b_ih[m],       bh_r = b_hh[m];
            const float bi_z = b_ih[100 + m], bh_z = b_hh[100 + m];
            const float bi_n = b_ih[200 + m], bh_n = b_hh[200 + m];
#pragma unroll
            for (int rg = 0; rg < 4; ++rg) {
#pragma unroll
                for (int reg = 0; reg < 4; ++reg) {
                    int row = 16 * rg + lk * 4 + reg;
                    size_t node = (size_t)s_node[row];
                    float mo = bf2f(Xs[row * RSL + m]);
                    float rgv = accA[0][rg][reg] + bi_r + bh_r;
                    float zgv = accA[1][rg][reg] + bi_z + bh_z;
                    float ghn = accA[2][rg][reg] + bh_n;
                    float gin = bi_n;
                    float rr = fsigmoid(rgv);
                    float zz = fsigmoid(zgv);
                    float nv = ftanh(gin + rr * ghn);
                    out_mem[node * MEMD + m] = (1.f - zz) * nv + zz * mo;
                }
            }
        }
    }
}

extern "C" void kernel_launch(void* const* d_in, const int* in_sizes, int n_in,
                              void* d_out, int out_size, void* d_ws, size_t ws_size,
                              hipStream_t stream) {
    const float* memory = (const float*)d_in[0];
    const float* raw_msg = (const float*)d_in[1];
    const float* time_w = (const float*)d_in[2];
    const float* time_b = (const float*)d_in[3];
    const float* w_ih = (const float*)d_in[4];
    const float* w_hh = (const float*)d_in[5];
    const float* b_ih = (const float*)d_in[6];
    const float* b_hh = (const float*)d_in[7];
    const int* last_update = (const int*)d_in[8];
    const int* src = (const int*)d_in[9];
    const int* dst = (const int*)d_in[10];
    const int* t = (const int*)d_in[11];

    char* ws = (char*)d_ws;
    unsigned long long* keys = (unsigned long long*)ws;       // 1,600,000 B @ 0
    int* othC = (int*)(ws + 1600000);                         //   800,000 B
    int* ewC = (int*)(ws + 2400000);                          //   800,000 B
    float* dtvC = (float*)(ws + 3200000);                     //   800,000 B
    unsigned short* Wb = (unsigned short*)(ws + 4000000);     //   408,576 B
    int* list = (int*)(ws + 4408576);                         //   800,000 B
    int* cnt = (int*)(ws + 5208576);                          //        16 B
    int* blkW = (int*)(ws + 5208592);                         //     3,128 B
    int* offW = (int*)(ws + 5211720);                         //     3,128 B

    float* out_mem = (float*)d_out;
    float* out_lu = (float*)d_out + (size_t)NN * MEMD;

    hipMemsetAsync(keys, 0, (size_t)NN * 8, stream);
    k_winner<<<NB2, 256, 0, stream>>>(src, dst, t, keys);
    k_count<<<NB2, 256, 0, stream>>>(keys, blkW);
    k_scan<<<1, 1024, 0, stream>>>(blkW, offW, cnt);
    k_scatter<<<NB2, 256, 0, stream>>>(keys, src, dst, last_update, offW,
                                       othC, ewC, dtvC, out_lu, list);
    k_pack<<<(NKT * NCT * 64 + 255) / 256, 256, 0, stream>>>(w_ih, w_hh, Wb);
    k_fusedWL<<<NBLKF, NTHR, 0, stream>>>(memory, raw_msg, time_w, time_b, b_ih, b_hh,
                                          othC, ewC, dtvC, Wb, list, cnt, out_mem);
}

// Round 21
// 145.751 us; speedup vs baseline: 1.2486x; 1.0292x over previous
//
#include <hip/hip_runtime.h>
#include <hip/hip_bf16.h>
#include <math.h>

#define NN 200000
#define EE 100000
#define RAWD 172
#define MEMD 100
#define NKT 19            // 15 gi k-tiles (K=480) + 4 gh k-tiles (reuse Xs[0,128))
#define NCT 21            // col-tiles: ct = p*7 + jm (gate-aligned), m = jm*16+i
#define BM 64             // winner nodes per block
#define BML 64            // loser nodes per block
#define NTHR 512          // 8 waves
#define RS 488            // winner X row stride (shorts)
#define RSL 136           // loser X row stride (shorts)
#define NB2 782           // ceil(NN/256)
#define NBLKF 6250        // ceil(NN/64) + ceil(NN/64)

typedef __attribute__((ext_vector_type(8))) short bf16x8;
typedef __attribute__((ext_vector_type(4))) float f32x4;

__device__ inline unsigned short f2bf(float v) {
    __hip_bfloat16 h = __float2bfloat16(v);
    unsigned short u; __builtin_memcpy(&u, &h, 2); return u;
}

__device__ inline ushort4 pack4(float4 v) {
    ushort4 r;
    r.x = f2bf(v.x); r.y = f2bf(v.y); r.z = f2bf(v.z); r.w = f2bf(v.w);
    return r;
}

__device__ inline float bf2f(unsigned short u) {
    unsigned int x = ((unsigned int)u) << 16;
    float f; __builtin_memcpy(&f, &x, 4); return f;
}

__device__ inline float fsigmoid(float x) { return 1.f / (1.f + __expf(-x)); }
__device__ inline float ftanh(float x) { return 1.f - 2.f / (__expf(2.f * x) + 1.f); }

// Branchless cos: f64 range reduction, f32 polys, quadrant select via bit tricks.
__device__ inline float fast_cos(float x) {
    double xd = (double)x;
    double kd = rint(xd * 0.6366197723675814);      // x * 2/pi
    double r_d = fma(kd, -1.5707963267948966, xd);  // x - k*pi/2
    float r = (float)r_d;
    int ki = (int)kd;
    float s = r * r;
    float c = fmaf(s, fmaf(s, fmaf(s, fmaf(s, 2.4801587e-5f, -1.3888889e-3f),
                                   4.1666668e-2f), -0.5f), 1.0f);
    float sn = r * fmaf(s, fmaf(s, fmaf(s, -1.9841270e-4f, 8.3333338e-3f),
                                -1.6666667e-1f), 1.0f);
    float base = (ki & 1) ? sn : c;
    return ((ki + 1) & 2) ? -base : base;
}

// ---- kernel 1: per-node winner via packed atomicMax key = (t<<32)|(eid+1) ----
__global__ void k_winner(const int* __restrict__ src, const int* __restrict__ dst,
                         const int* __restrict__ t, unsigned long long* __restrict__ keys) {
    int e = blockIdx.x * blockDim.x + threadIdx.x;
    if (e >= 2 * EE) return;
    int re = (e < EE) ? e : e - EE;
    int node = (e < EE) ? src[re] : dst[re];
    unsigned long long key =
        ((unsigned long long)(unsigned)t[re] << 32) | (unsigned)(e + 1);
    atomicMax(&keys[node], key);
}

// ---- kernel 2a: per-256-block winner counts ----
__global__ void k_count(const unsigned long long* __restrict__ keys,
                        int* __restrict__ blkW) {
    int n = blockIdx.x * 256 + threadIdx.x;
    bool f = (n < NN) && (keys[n] != 0ull);
    unsigned long long m = __ballot(f);
    __shared__ int s[4];
    int wave = threadIdx.x >> 6;
    if ((threadIdx.x & 63) == 0) s[wave] = __popcll(m);
    __syncthreads();
    if (threadIdx.x == 0) blkW[blockIdx.x] = s[0] + s[1] + s[2] + s[3];
}

// ---- kernel 2b: single-block exclusive scan ----
__global__ void k_scan(const int* __restrict__ blkW, int* __restrict__ offW,
                       int* __restrict__ cnt) {
    __shared__ int s[1024];
    int tid = threadIdx.x;
    int v = (tid < NB2) ? blkW[tid] : 0;
    s[tid] = v;
    __syncthreads();
    for (int off = 1; off < 1024; off <<= 1) {
        int t = (tid >= off) ? s[tid - off] : 0;
        __syncthreads();
        s[tid] += t;
        __syncthreads();
    }
    if (tid < NB2) offW[tid] = s[tid] - v;
    if (tid == 0) { cnt[0] = s[1023]; cnt[1] = NN - s[1023]; }
}

// ---- kernel 2c: ordered scatter + decode + compacted aux ----
__global__ void k_scatter(const unsigned long long* __restrict__ keys,
                          const int* __restrict__ src, const int* __restrict__ dst,
                          const int* __restrict__ lu, const int* __restrict__ offW,
                          int* __restrict__ othC, int* __restrict__ ewC,
                          float* __restrict__ dtvC, float* __restrict__ out_lu,
                          int* __restrict__ list) {
    int bid = blockIdx.x, tid = threadIdx.x;
    int n = bid * 256 + tid;
    bool valid = n < NN;
    unsigned long long k = valid ? keys[n] : 0ull;
    bool fW = valid && (k != 0ull);
    bool fL = valid && (k == 0ull);
    unsigned long long mW = __ballot(fW), mL = __ballot(fL);
    int lane = tid & 63, wave = tid >> 6;
    __shared__ int sW[4], sL[4];
    if (lane == 0) { sW[wave] = __popcll(mW); sL[wave] = __popcll(mL); }
    __syncthreads();
    int baseW = 0, baseL = 0;
    for (int i = 0; i < wave; ++i) { baseW += sW[i]; baseL += sL[i]; }
    unsigned long long below = (1ull << lane) - 1ull;
    if (fW) {
        int pos = offW[bid] + baseW + __popcll(mW & below);
        list[pos] = n;
        int w = (int)(k & 0xffffffffull) - 1;
        int re = (w < EE) ? w : w - EE;
        othC[pos] = (w < EE) ? dst[re] : src[re];
        ewC[pos] = re;
        int tt = (int)(k >> 32);
        dtvC[pos] = (float)tt - (float)lu[n];
        out_lu[n] = (float)tt;
    } else if (valid) {
        int pos = (bid * 256 - offW[bid]) + baseL + __popcll(mL & below);
        list[NN - 1 - pos] = n;
        out_lu[n] = (float)lu[n];
    }
}

// ---- kernel 3: pack W, bf16, gate-aligned cols; tiles 15..18 = w_hh local-k ----
__global__ void k_pack(const float* __restrict__ w_ih, const float* __restrict__ w_hh,
                       unsigned short* __restrict__ Wb) {
    int id = blockIdx.x * blockDim.x + threadIdx.x;
    if (id >= NKT * NCT * 64) return;
    int lane = id & 63;
    int ct = (id >> 6) % NCT;
    int kt = id / (64 * NCT);
    int jm = ct % 7, p = ct / 7;
    int m = jm * 16 + (lane & 15);
    int kl = lane >> 4;
    unsigned short o[8];
#pragma unroll
    for (int j = 0; j < 8; ++j) {
        float v = 0.f;
        if (m < MEMD) {
            int c = p * MEMD + m;
            if (kt < 15) {
                int k = kt * 32 + kl * 8 + j;
                if (k < 472) v = w_ih[(size_t)c * 472 + k];
            } else {
                int kk = (kt - 15) * 32 + kl * 8 + j;
                if (kk < MEMD) v = w_hh[(size_t)c * MEMD + kk];
            }
        }
        o[j] = f2bf(v);
    }
    uint4 v4; __builtin_memcpy(&v4, o, 16);
    *reinterpret_cast<uint4*>(Wb + (size_t)id * 8) = v4;
}

// ---- kernel 4: merged winner/loser; reg-staged build (R18 best-measured) ----
__global__ __launch_bounds__(NTHR, 3) void k_fusedWL(
    const float* __restrict__ memory, const float* __restrict__ raw_msg,
    const float* __restrict__ time_w, const float* __restrict__ time_b,
    const float* __restrict__ b_ih, const float* __restrict__ b_hh,
    const int* __restrict__ othC, const int* __restrict__ ewC,
    const float* __restrict__ dtvC, const unsigned short* __restrict__ Wb,
    const int* __restrict__ list, const int* __restrict__ cnt,
    float* __restrict__ out_mem) {
    __shared__ alignas(16) unsigned short Xs[BM * RS];   // 62464 B
    __shared__ int s_node[BM];
    __shared__ int s_oth[BM];
    __shared__ int s_e[BM];
    __shared__ float s_dt[BM];

    const int tid = threadIdx.x;
    const int nW = cnt[0];
    const int wblk = (nW + BM - 1) / BM;
    const int w = tid >> 6;
    const int l = tid & 63;
    const int lrow = l & 15, lk = l >> 4;
    const bf16x8* Wbv = reinterpret_cast<const bf16x8*>(Wb);
    const ushort4 z4 = {0, 0, 0, 0};

    auto loadB = [&](bf16x8 (&bb)[3], int kt) {
#pragma unroll
        for (int p = 0; p < 3; ++p)
            bb[p] = Wbv[(kt * NCT + p * 7 + w) * 64 + l];
    };

    if ((int)blockIdx.x < wblk) {
        // ================= winner path =================
        const int r15 = blockIdx.x % 15;
        const int r4 = blockIdx.x & 3;
        auto ktof = [&](int idx) {
            if (idx < 15) { int k = r15 + idx; return k >= 15 ? k - 15 : k; }
            int k = r4 + (idx - 15); return 15 + (k >= 4 ? k - 4 : k);
        };

        // 2-deep B prefetch, issued BEFORE build
        bf16x8 b0[3], b1[3];
        if (w < 7) { loadB(b0, ktof(0)); loadB(b1, ktof(1)); }

        const int nbase = blockIdx.x * BM;
        if (tid < BM) {
            int idx = nbase + tid; if (idx >= nW) idx = nW - 1;  // dup tail: benign
            s_node[tid] = list[idx];
            s_oth[tid] = othC[idx];
            s_e[tid] = ewC[idx];
            s_dt[tid] = dtvC[idx];
        }
        __syncthreads();

        // ---- reg-staged build: issue ALL 14 gather loads first ----
        float4 vO[4], vR[6], vS[4];
#pragma unroll
        for (int f = 0; f < 4; ++f) {
            int i = tid + f * NTHR; int i2 = (i < BM * 25) ? i : 0;
            int row = i2 / 25, c = i2 - row * 25;
            vO[f] = *reinterpret_cast<const float4*>(
                memory + (size_t)s_oth[row] * MEMD + 4 * c);
        }
#pragma unroll
        for (int f = 0; f < 6; ++f) {
            int i = tid + f * NTHR; int i2 = (i < BM * 43) ? i : 0;
            int row = i2 / 43, c = i2 - row * 43;
            vR[f] = *reinterpret_cast<const float4*>(
                raw_msg + (size_t)s_e[row] * RAWD + 4 * c);
        }
#pragma unroll
        for (int f = 0; f < 4; ++f) {
            int i = tid + f * NTHR; int i2 = (i < BM * 25) ? i : 0;
            int row = i2 / 25, c = i2 - row * 25;
            vS[f] = *reinterpret_cast<const float4*>(
                memory + (size_t)s_node[row] * MEMD + 4 * c);
        }
        // Forbid sinking loads into the store phase.
        asm volatile("" ::: "memory");
        // ---- store phase: pack + ds_write ----
#pragma unroll
        for (int f = 0; f < 4; ++f) {
            int i = tid + f * NTHR;
            if (i < BM * 25) {
                int row = i / 25, c = i - row * 25;
                *reinterpret_cast<ushort4*>(&Xs[row * RS + 100 + 4 * c]) = pack4(vO[f]);
            }
        }
#pragma unroll
        for (int f = 0; f < 6; ++f) {
            int i = tid + f * NTHR;
            if (i < BM * 43) {
                int row = i / 43, c = i - row * 43;
                *reinterpret_cast<ushort4*>(&Xs[row * RS + 200 + 4 * c]) = pack4(vR[f]);
            }
        }
#pragma unroll
        for (int f = 0; f < 4; ++f) {
            int i = tid + f * NTHR;
            if (i < BM * 25) {
                int row = i / 25, c = i - row * 25;
                *reinterpret_cast<ushort4*>(&Xs[row * RS + 4 * c]) = pack4(vS[f]);
            }
        }
        // enc: VALU-only
#pragma unroll
        for (int f = 0; f < 4; ++f) {
            int i = tid + f * NTHR;
            if (i < BM * 25) {
                int row = i / 25, c = i - row * 25;
                float dt = s_dt[row];
                float4 wv = *reinterpret_cast<const float4*>(time_w + 4 * c);
                float4 bv = *reinterpret_cast<const float4*>(time_b + 4 * c);
                float4 v;
                v.x = fast_cos(__fadd_rn(__fmul_rn(dt, wv.x), bv.x));
                v.y = fast_cos(__fadd_rn(__fmul_rn(dt, wv.y), bv.y));
                v.z = fast_cos(__fadd_rn(__fmul_rn(dt, wv.z), bv.z));
                v.w = fast_cos(__fadd_rn(__fmul_rn(dt, wv.w), bv.w));
                *reinterpret_cast<ushort4*>(&Xs[row * RS + 372 + 4 * c]) = pack4(v);
            }
        }
        if (tid < BM * 2) {
            int row = tid >> 1, c = tid & 1;
            *reinterpret_cast<ushort4*>(&Xs[row * RS + 472 + 4 * c]) = z4;
        }
        __syncthreads();
        if (w >= 7) return;   // wave 7 idle; no barriers follow

        f32x4 accA[3][4];     // [gate p][rowgroup]
        f32x4 acch[4];        // gh-only n-gate accumulator
#pragma unroll
        for (int p = 0; p < 3; ++p)
#pragma unroll
            for (int rg = 0; rg < 4; ++rg) accA[p][rg] = (f32x4){0.f, 0.f, 0.f, 0.f};
#pragma unroll
        for (int rg = 0; rg < 4; ++rg) acch[rg] = (f32x4){0.f, 0.f, 0.f, 0.f};

        auto step = [&](bf16x8 (&bb)[3], int kt) {
            int ao = (kt < 15) ? kt * 32 : (kt - 15) * 32;   // gh tiles reuse Xs[0,128)
            bf16x8 a[4];
#pragma unroll
            for (int rg = 0; rg < 4; ++rg)
                a[rg] = *reinterpret_cast<const bf16x8*>(
                    &Xs[(16 * rg + lrow) * RS + ao + lk * 8]);
#pragma unroll
            for (int p = 0; p < 3; ++p)
#pragma unroll
                for (int rg = 0; rg < 4; ++rg)
                    accA[p][rg] = __builtin_amdgcn_mfma_f32_16x16x32_bf16(a[rg], bb[p], accA[p][rg], 0, 0, 0);
            if (kt >= 15) {
#pragma unroll
                for (int rg = 0; rg < 4; ++rg)
                    acch[rg] = __builtin_amdgcn_mfma_f32_16x16x32_bf16(a[rg], bb[2], acch[rg], 0, 0, 0);
            }
        };

#pragma unroll
        for (int g = 0; g < 18; g += 2) {
            step(b0, ktof(g));     if (g + 2 < NKT) loadB(b0, ktof(g + 2));
            step(b1, ktof(g + 1)); if (g + 3 < NKT) loadB(b1, ktof(g + 3));
        }
        step(b0, ktof(18));

        // register-local epilogue; memory re-read from Xs (bf16)
        const int m = 16 * w + lrow;
        if (m < MEMD) {
            const float bi_r = b_ih[m],       bh_r = b_hh[m];
            const float bi_z = b_ih[100 + m], bh_z = b_hh[100 + m];
            const float bi_n = b_ih[200 + m], bh_n = b_hh[200 + m];
#pragma unroll
            for (int rg = 0; rg < 4; ++rg) {
#pragma unroll
                for (int reg = 0; reg < 4; ++reg) {
                    int row = 16 * rg + lk * 4 + reg;
                    size_t node = (size_t)s_node[row];
                    float mo = bf2f(Xs[row * RS + m]);
                    float rgv = accA[0][rg][reg] + bi_r + bh_r;
                    float zgv = accA[1][rg][reg] + bi_z + bh_z;
                    float ghn = acch[rg][reg] + bh_n;
                    float gin = (accA[2][rg][reg] - acch[rg][reg]) + bi_n;
                    float rr = fsigmoid(rgv);
                    float zz = fsigmoid(zgv);
                    float nv = ftanh(gin + rr * ghn);
                    out_mem[node * MEMD + m] = (1.f - zz) * nv + zz * mo;
                }
            }
        }
    } else {
        // ================= loser path =================
        const int nL = NN - nW;
        const int lbase = ((int)blockIdx.x - wblk) * BML;
        if (lbase >= nL) return;

        const int r4 = blockIdx.x & 3;
        auto lkt = [&](int idx) { return (r4 + idx) & 3; };

        bf16x8 bl0[3], bl1[3];
        if (w < 7) { loadB(bl0, 15 + lkt(0)); loadB(bl1, 15 + lkt(1)); }

        if (tid < BML) {
            int idx = lbase + tid; if (idx >= nL) idx = nL - 1;  // dup tail: benign
            s_node[tid] = list[NN - 1 - idx];
        }
        __syncthreads();

        // reg-staged self-mem load (MLP~4), forced phase separation
        float4 vS[4];
#pragma unroll
        for (int f = 0; f < 4; ++f) {
            int i = tid + f * NTHR; int i2 = (i < BML * 25) ? i : 0;
            int row = i2 / 25, c = i2 - row * 25;
            vS[f] = *reinterpret_cast<const float4*>(
                memory + (size_t)s_node[row] * MEMD + 4 * c);
        }
        asm volatile("" ::: "memory");
#pragma unroll
        for (int f = 0; f < 4; ++f) {
            int i = tid + f * NTHR;
            if (i < BML * 25) {
                int row = i / 25, c = i - row * 25;
                *reinterpret_cast<ushort4*>(&Xs[row * RSL + 4 * c]) = pack4(vS[f]);
            }
        }
        if (tid < BML * 7) {
            int row = tid / 7, c = tid - row * 7;
            *reinterpret_cast<ushort4*>(&Xs[row * RSL + 100 + 4 * c]) = z4;
        }
        __syncthreads();
        if (w >= 7) return;

        f32x4 accA[3][4];
#pragma unroll
        for (int p = 0; p < 3; ++p)
#pragma unroll
            for (int rg = 0; rg < 4; ++rg) accA[p][rg] = (f32x4){0.f, 0.f, 0.f, 0.f};

        auto stepL = [&](bf16x8 (&bb)[3], int ktl) {
            bf16x8 a[4];
#pragma unroll
            for (int rg = 0; rg < 4; ++rg)
                a[rg] = *reinterpret_cast<const bf16x8*>(
                    &Xs[(16 * rg + lrow) * RSL + ktl * 32 + lk * 8]);
#pragma unroll
            for (int p = 0; p < 3; ++p)
#pragma unroll
                for (int rg = 0; rg < 4; ++rg)
                    accA[p][rg] = __builtin_amdgcn_mfma_f32_16x16x32_bf16(a[rg], bb[p], accA[p][rg], 0, 0, 0);
        };

        stepL(bl0, lkt(0)); loadB(bl0, 15 + lkt(2));
        stepL(bl1, lkt(1)); loadB(bl1, 15 + lkt(3));
        stepL(bl0, lkt(2));
        stepL(bl1, lkt(3));

        const int m = 16 * w + lrow;
        if (m < MEMD) {
            const float bi_r = b_ih[m],       bh_r = b_hh[m];
            const float bi_z = b_ih[100 + m], bh_z = b_hh[100 + m];
            const float bi_n = b_ih[200 + m], bh_n = b_hh[200 + m];
#pragma unroll
            for (int rg = 0; rg < 4; ++rg) {
#pragma unroll
                for (int reg = 0; reg < 4; ++reg) {
                    int row = 16 * rg + lk * 4 + reg;
                    size_t node = (size_t)s_node[row];
                    float mo = bf2f(Xs[row * RSL + m]);
                    float rgv = accA[0][rg][reg] + bi_r + bh_r;
                    float zgv = accA[1][rg][reg] + bi_z + bh_z;
                    float ghn = accA[2][rg][reg] + bh_n;
                    float gin = bi_n;
                    float rr = fsigmoid(rgv);
                    float zz = fsigmoid(zgv);
                    float nv = ftanh(gin + rr * ghn);
                    out_mem[node * MEMD + m] = (1.f - zz) * nv + zz * mo;
                }
            }
        }
    }
}

extern "C" void kernel_launch(void* const* d_in, const int* in_sizes, int n_in,
                              void* d_out, int out_size, void* d_ws, size_t ws_size,
                              hipStream_t stream) {
    const float* memory = (const float*)d_in[0];
    const float* raw_msg = (const float*)d_in[1];
    const float* time_w = (const float*)d_in[2];
    const float* time_b = (const float*)d_in[3];
    const float* w_ih = (const float*)d_in[4];
    const float* w_hh = (const float*)d_in[5];
    const float* b_ih = (const float*)d_in[6];
    const float* b_hh = (const float*)d_in[7];
    const int* last_update = (const int*)d_in[8];
    const int* src = (const int*)d_in[9];
    const int* dst = (const int*)d_in[10];
    const int* t = (const int*)d_in[11];

    char* ws = (char*)d_ws;
    unsigned long long* keys = (unsigned long long*)ws;       // 1,600,000 B @ 0
    int* othC = (int*)(ws + 1600000);                         //   800,000 B
    int* ewC = (int*)(ws + 2400000);                          //   800,000 B
    float* dtvC = (float*)(ws + 3200000);                     //   800,000 B
    unsigned short* Wb = (unsigned short*)(ws + 4000000);     //   408,576 B
    int* list = (int*)(ws + 4408576);                         //   800,000 B
    int* cnt = (int*)(ws + 5208576);                          //        16 B
    int* blkW = (int*)(ws + 5208592);                         //     3,128 B
    int* offW = (int*)(ws + 5211720);                         //     3,128 B

    float* out_mem = (float*)d_out;
    float* out_lu = (float*)d_out + (size_t)NN * MEMD;

    hipMemsetAsync(keys, 0, (size_t)NN * 8, stream);
    k_winner<<<NB2, 256, 0, stream>>>(src, dst, t, keys);
    k_count<<<NB2, 256, 0, stream>>>(keys, blkW);
    k_scan<<<1, 1024, 0, stream>>>(blkW, offW, cnt);
    k_scatter<<<NB2, 256, 0, stream>>>(keys, src, dst, last_update, offW,
                                       othC, ewC, dtvC, out_lu, list);
    k_pack<<<(NKT * NCT * 64 + 255) / 256, 256, 0, stream>>>(w_ih, w_hh, Wb);
    k_fusedWL<<<NBLKF, NTHR, 0, stream>>>(memory, raw_msg, time_w, time_b, b_ih, b_hh,
                                          othC, ewC, dtvC, Wb, list, cnt, out_mem);
}